// Round 1
// baseline (227.021 us; speedup 1.0000x reference)
//
#include <hip/hip_runtime.h>

#define B 128
#define L 1024

// Abramowitz & Stegun 7.1.26: erfc(x) for x>=0, |err| <= 1.5e-7.
// Branch-free extension to x<0 via erfc(-x) = 2 - erfc(x).
__device__ __forceinline__ float fast_erfc(float x) {
    float ax = __builtin_fabsf(x);
    float t  = __builtin_amdgcn_rcpf(__builtin_fmaf(0.3275911f, ax, 1.0f));
    float p  = __builtin_fmaf(t, 1.061405429f, -1.453152027f);
    p = __builtin_fmaf(t, p, 1.421413741f);
    p = __builtin_fmaf(t, p, -0.284496736f);
    p = __builtin_fmaf(t, p, 0.254829592f);
    p = p * t;
    float e = __expf(-ax * ax);
    float r = p * e;
    return x < 0.0f ? 2.0f - r : r;
}

__global__ __launch_bounds__(128) void zero_ws(float* ws) {
    ws[threadIdx.x] = 0.0f;
}

// grid = B*4 blocks, 256 threads. Block (b, seg) computes dcg contributions
// for i in [seg*256, seg*256+256) of row b; atomicAdd partial sum to dcg[b].
__global__ __launch_bounds__(256) void dcg_kernel(const float* __restrict__ preds,
                                                  const float* __restrict__ target,
                                                  float* __restrict__ dcg) {
    __shared__ float sp[L];
    __shared__ float red[256];

    const int b   = blockIdx.x >> 2;
    const int seg = blockIdx.x & 3;
    const float* row = preds + b * L;

    // stage the row in LDS (coalesced float4 loads)
    for (int k = threadIdx.x; k < L / 4; k += 256) {
        reinterpret_cast<float4*>(sp)[k] = reinterpret_cast<const float4*>(row)[k];
    }
    __syncthreads();

    const int i = seg * 256 + threadIdx.x;
    const float pi = sp[i];

    float s0 = 0.0f, s1 = 0.0f, s2 = 0.0f, s3 = 0.0f;
    #pragma unroll 4
    for (int j = 0; j < L; j += 4) {
        float4 v = *reinterpret_cast<const float4*>(&sp[j]);
        s0 += fast_erfc((v.x - pi) * 0.5f);
        s1 += fast_erfc((v.y - pi) * 0.5f);
        s2 += fast_erfc((v.z - pi) * 0.5f);
        s3 += fast_erfc((v.w - pi) * 0.5f);
    }
    float sum = (s0 + s1) + (s2 + s3);
    // expected rank: 1 + 0.5*(sum - erfc(0)) ; erfc(0)=1 (diagonal term)
    float er = 0.5f + 0.5f * sum;

    float g = __expf(target[b * L + i] * 0.6931471805599453f) - 1.0f;  // 2^t - 1 (t integer 0..4)
    float contrib = g / log2f(er + 1.0f);

    red[threadIdx.x] = contrib;
    __syncthreads();
    #pragma unroll
    for (int s = 128; s > 0; s >>= 1) {
        if (threadIdx.x < (unsigned)s) red[threadIdx.x] += red[threadIdx.x + s];
        __syncthreads();
    }
    if (threadIdx.x == 0) atomicAdd(&dcg[b], red[0]);
}

// One block, 128 threads: thread b computes idcg[b] via counting sort
// (grades are integers 0..4), then ndcg[b]; block-reduce -> out[0] = -mean.
__global__ __launch_bounds__(128) void finish_kernel(const float* __restrict__ target,
                                                     const float* __restrict__ dcg,
                                                     float* __restrict__ out) {
    __shared__ float red[128];
    const int b = threadIdx.x;
    const float* row = target + b * L;

    int n4 = 0, n3 = 0, n2 = 0, n1 = 0;   // cumulative counts of grades >=4,>=3,>=2,>=1
    for (int j = 0; j < L; ++j) {
        float t = row[j];
        n4 += (t > 3.5f);
        n3 += (t > 2.5f);
        n2 += (t > 1.5f);
        n1 += (t > 0.5f);
    }

    float idcg = 0.0f;
    for (int pos = 1; pos <= n1; ++pos) {
        float gain = (pos <= n4) ? 15.0f : (pos <= n3) ? 7.0f : (pos <= n2) ? 3.0f : 1.0f;
        idcg += gain / log2f((float)pos + 1.0f);
    }

    float ndcg = dcg[b] / (idcg + 1e-10f);

    red[b] = ndcg;
    __syncthreads();
    #pragma unroll
    for (int s = 64; s > 0; s >>= 1) {
        if (b < s) red[b] += red[b + s];
        __syncthreads();
    }
    if (b == 0) out[0] = -red[0] * (1.0f / (float)B);
}

extern "C" void kernel_launch(void* const* d_in, const int* in_sizes, int n_in,
                              void* d_out, int out_size, void* d_ws, size_t ws_size,
                              hipStream_t stream) {
    const float* preds  = (const float*)d_in[0];
    const float* target = (const float*)d_in[1];
    float* out = (float*)d_out;
    float* dcg = (float*)d_ws;   // B floats

    zero_ws<<<1, 128, 0, stream>>>(dcg);
    dcg_kernel<<<B * 4, 256, 0, stream>>>(preds, target, dcg);
    finish_kernel<<<1, 128, 0, stream>>>(target, dcg, out);
}

// Round 2
// 118.978 us; speedup vs baseline: 1.9081x; 1.9081x over previous
//
#include <hip/hip_runtime.h>

#define B 128
#define L 1024

// Abramowitz & Stegun 7.1.26: erfc(x) for x>=0, |err| <= 1.5e-7.
// Branch-free extension to x<0 via erfc(-x) = 2 - erfc(x).
__device__ __forceinline__ float fast_erfc(float x) {
    float ax = __builtin_fabsf(x);
    float t  = __builtin_amdgcn_rcpf(__builtin_fmaf(0.3275911f, ax, 1.0f));
    float p  = __builtin_fmaf(t, 1.061405429f, -1.453152027f);
    p = __builtin_fmaf(t, p, 1.421413741f);
    p = __builtin_fmaf(t, p, -0.284496736f);
    p = __builtin_fmaf(t, p, 0.254829592f);
    p = p * t;
    float e = __expf(-ax * ax);
    float r = p * e;
    return x < 0.0f ? 2.0f - r : r;
}

// ws layout: [0..B) dcg[b], [B] ndcg sum accumulator
__global__ __launch_bounds__(256) void zero_ws(float* ws) {
    ws[threadIdx.x] = 0.0f;
}

// grid = B*4 blocks, 256 threads. Block (b, seg) computes dcg contributions
// for i in [seg*256, seg*256+256) of row b; atomicAdd partial sum to dcg[b].
__global__ __launch_bounds__(256) void dcg_kernel(const float* __restrict__ preds,
                                                  const float* __restrict__ target,
                                                  float* __restrict__ dcg) {
    __shared__ float sp[L];
    __shared__ float red[256];

    const int b   = blockIdx.x >> 2;
    const int seg = blockIdx.x & 3;
    const float* row = preds + b * L;

    // stage the row in LDS (coalesced float4 loads)
    for (int k = threadIdx.x; k < L / 4; k += 256) {
        reinterpret_cast<float4*>(sp)[k] = reinterpret_cast<const float4*>(row)[k];
    }
    __syncthreads();

    const int i = seg * 256 + threadIdx.x;
    const float pi = sp[i];

    float s0 = 0.0f, s1 = 0.0f, s2 = 0.0f, s3 = 0.0f;
    #pragma unroll 4
    for (int j = 0; j < L; j += 4) {
        float4 v = *reinterpret_cast<const float4*>(&sp[j]);
        s0 += fast_erfc((v.x - pi) * 0.5f);
        s1 += fast_erfc((v.y - pi) * 0.5f);
        s2 += fast_erfc((v.z - pi) * 0.5f);
        s3 += fast_erfc((v.w - pi) * 0.5f);
    }
    float sum = (s0 + s1) + (s2 + s3);
    // expected rank: 1 + 0.5*(sum - erfc(0)) ; erfc(0)=1 (diagonal term)
    float er = 0.5f + 0.5f * sum;

    float g = __expf(target[b * L + i] * 0.6931471805599453f) - 1.0f;  // 2^t - 1
    float contrib = g / log2f(er + 1.0f);

    red[threadIdx.x] = contrib;
    __syncthreads();
    #pragma unroll
    for (int s = 128; s > 0; s >>= 1) {
        if (threadIdx.x < (unsigned)s) red[threadIdx.x] += red[threadIdx.x + s];
        __syncthreads();
    }
    if (threadIdx.x == 0) atomicAdd(&dcg[b], red[0]);
}

// grid = B blocks, 256 threads. Block b: counting-sort grade counts (grades
// are integers 0..4), parallel IDCG over positions, ndcg[b] -> atomicAdd sum.
__global__ __launch_bounds__(256) void idcg_ndcg_kernel(const float* __restrict__ target,
                                                        const float* __restrict__ dcg,
                                                        float* __restrict__ ws) {
    __shared__ unsigned long long cred[256];
    __shared__ float fred[256];

    const int b = blockIdx.x;
    const float* row = target + b * L;
    const int tid = threadIdx.x;

    // local counts of grades >=4,>=3,>=2,>=1 packed 16-bit each (max 1024 fits)
    unsigned long long cnt = 0ull;
    #pragma unroll
    for (int k = 0; k < 4; ++k) {
        float t = row[tid + k * 256];
        cnt += ((unsigned long long)(t > 3.5f) << 48)
             + ((unsigned long long)(t > 2.5f) << 32)
             + ((unsigned long long)(t > 1.5f) << 16)
             + ((unsigned long long)(t > 0.5f));
    }
    cred[tid] = cnt;
    __syncthreads();
    #pragma unroll
    for (int s = 128; s > 0; s >>= 1) {
        if (tid < (unsigned)s) cred[tid] += cred[tid + s];
        __syncthreads();
    }
    unsigned long long tot = cred[0];
    const int n4 = (int)(tot >> 48) & 0xFFFF;
    const int n3 = (int)(tot >> 32) & 0xFFFF;
    const int n2 = (int)(tot >> 16) & 0xFFFF;
    const int n1 = (int)(tot)       & 0xFFFF;

    // parallel IDCG: positions tid+1, tid+257, tid+513, tid+769
    float is = 0.0f;
    #pragma unroll
    for (int k = 0; k < 4; ++k) {
        int pos = tid + 1 + k * 256;
        float gain = (pos <= n4) ? 15.0f : (pos <= n3) ? 7.0f :
                     (pos <= n2) ? 3.0f  : (pos <= n1) ? 1.0f : 0.0f;
        is += gain / log2f((float)pos + 1.0f);
    }
    fred[tid] = is;
    __syncthreads();
    #pragma unroll
    for (int s = 128; s > 0; s >>= 1) {
        if (tid < (unsigned)s) fred[tid] += fred[tid + s];
        __syncthreads();
    }
    if (tid == 0) {
        float ndcg = dcg[b] / (fred[0] + 1e-10f);
        atomicAdd(&ws[B], ndcg);
    }
}

__global__ __launch_bounds__(64) void writeout_kernel(const float* __restrict__ ws,
                                                      float* __restrict__ out) {
    if (threadIdx.x == 0) out[0] = -ws[B] * (1.0f / (float)B);
}

extern "C" void kernel_launch(void* const* d_in, const int* in_sizes, int n_in,
                              void* d_out, int out_size, void* d_ws, size_t ws_size,
                              hipStream_t stream) {
    const float* preds  = (const float*)d_in[0];
    const float* target = (const float*)d_in[1];
    float* out = (float*)d_out;
    float* ws  = (float*)d_ws;   // B dcg values + 1 accumulator

    zero_ws<<<1, 256, 0, stream>>>(ws);
    dcg_kernel<<<B * 4, 256, 0, stream>>>(preds, target, ws);
    idcg_ndcg_kernel<<<B, 256, 0, stream>>>(target, ws, ws);
    writeout_kernel<<<1, 64, 0, stream>>>(ws, out);
}

// Round 3
// 96.855 us; speedup vs baseline: 2.3439x; 1.2284x over previous
//
#include <hip/hip_runtime.h>

#define B 128
#define L 1024

// ws layout (floats):
//   [0 .. 2048)  per-wave dcg partials: index b*16 + iseg*4 + wave
//   [2048]       ndcg accumulator (zeroed by pair_kernel block 0)
//   [2049]       completion counter (int, zeroed by pair_kernel block 0)

#if __has_builtin(__builtin_amdgcn_exp2f)
#define EXP2(x) __builtin_amdgcn_exp2f(x)
#else
#define EXP2(x) __expf((x) * 0.6931471805599453f)
#endif

// Bowling logistic approximation: Phi(z) ~= 1/(1+exp(-1.5976 z - 0.07056 z^3)),
// max abs error ~1.4e-4. Constants pre-folded with log2(e) for v_exp_f32.
// 6 full-rate VALU + v_exp + v_rcp per call.
__device__ __forceinline__ float phi_sigmoid(float z) {
    float z2 = z * z;
    float q  = __builtin_fmaf(z2, -0.10179656f, -2.3048496f); // -(0.07056, 1.5976)*log2e
    float w  = z * q;                                         // = -(1.5976 z + 0.07056 z^3)*log2e
    float e  = EXP2(w);                                       // exp(-(...))
    return __builtin_amdgcn_rcpf(1.0f + e);
}

// grid = B*4 blocks, 256 threads. Block (b, iseg): i in [iseg*256, iseg*256+256),
// full j range staged in LDS (prescaled by 1/sqrt2). Per-wave partial dcg sums
// written to disjoint ws slots (no atomics, no zeroing needed).
__global__ __launch_bounds__(256) void pair_kernel(const float* __restrict__ preds,
                                                   const float* __restrict__ target,
                                                   float* __restrict__ ws) {
    __shared__ float sp[L];

    const int b    = blockIdx.x >> 2;
    const int iseg = blockIdx.x & 3;
    const int tid  = threadIdx.x;
    const float* row = preds + b * L;

    if (blockIdx.x == 0 && tid == 0) {
        ws[2048] = 0.0f;              // ndcg accumulator
        ((int*)ws)[2049] = 0;         // completion counter
    }

    // stage the row in LDS, prescaled by 1/sqrt(2): z = pi_s - pj_s directly
    float4 v4 = reinterpret_cast<const float4*>(row)[tid];
    const float inv_sqrt2 = 0.70710678118654752f;
    v4.x *= inv_sqrt2; v4.y *= inv_sqrt2; v4.z *= inv_sqrt2; v4.w *= inv_sqrt2;
    reinterpret_cast<float4*>(sp)[tid] = v4;

    const int i = iseg * 256 + tid;
    float tgt = target[b * L + i];    // hoisted global load

    __syncthreads();

    const float pi = sp[i];

    float s0 = 0.0f, s1 = 0.0f, s2 = 0.0f, s3 = 0.0f;
    #pragma unroll 4
    for (int j = 0; j < L; j += 4) {
        float4 v = *reinterpret_cast<const float4*>(&sp[j]);
        s0 += phi_sigmoid(pi - v.x);
        s1 += phi_sigmoid(pi - v.y);
        s2 += phi_sigmoid(pi - v.z);
        s3 += phi_sigmoid(pi - v.w);
    }
    float s = (s0 + s1) + (s2 + s3);
    // sum includes diagonal Phi(0)=0.5 exactly; er = 1 + (s - 0.5); er+1 = 1.5+s
    float er1 = 1.5f + s;

    float g = EXP2(tgt) - 1.0f;       // 2^t - 1, exact for integer grades
    float contrib = g * __builtin_amdgcn_rcpf(__log2f(er1));

    // wave-level reduction (no LDS, no barriers)
    #pragma unroll
    for (int off = 32; off > 0; off >>= 1)
        contrib += __shfl_down(contrib, off);
    if ((tid & 63) == 0)
        ws[b * 16 + iseg * 4 + (tid >> 6)] = contrib;
}

// grid = B blocks, 256 threads. Block b: counting-sort grade counts -> IDCG,
// combine 16 dcg partials, ndcg, then last-block-done finalization.
__global__ __launch_bounds__(256) void finish_kernel(const float* __restrict__ target,
                                                     float* __restrict__ ws,
                                                     float* __restrict__ out) {
    __shared__ unsigned long long cred[256];
    __shared__ float2 fred[256];

    const int b   = blockIdx.x;
    const int tid = threadIdx.x;
    const float* row = target + b * L;

    // packed 16-bit counts of grades >=4,>=3,>=2,>=1 (max 1024 fits in 16 bits)
    unsigned long long cnt = 0ull;
    #pragma unroll
    for (int k = 0; k < 4; ++k) {
        float t = row[tid + k * 256];
        cnt += ((unsigned long long)(t > 3.5f) << 48)
             + ((unsigned long long)(t > 2.5f) << 32)
             + ((unsigned long long)(t > 1.5f) << 16)
             + ((unsigned long long)(t > 0.5f));
    }
    cred[tid] = cnt;
    __syncthreads();
    #pragma unroll
    for (int s = 128; s > 0; s >>= 1) {
        if (tid < (unsigned)s) cred[tid] += cred[tid + s];
        __syncthreads();
    }
    unsigned long long tot = cred[0];
    const int n4 = (int)(tot >> 48) & 0xFFFF;
    const int n3 = (int)(tot >> 32) & 0xFFFF;
    const int n2 = (int)(tot >> 16) & 0xFFFF;
    const int n1 = (int)(tot)       & 0xFFFF;

    // parallel IDCG over positions; combined reduction with dcg partials
    float idcg_p = 0.0f;
    #pragma unroll
    for (int k = 0; k < 4; ++k) {
        int pos = tid + 1 + k * 256;
        float gain = (pos <= n4) ? 15.0f : (pos <= n3) ? 7.0f :
                     (pos <= n2) ? 3.0f  : (pos <= n1) ? 1.0f : 0.0f;
        idcg_p += gain * __builtin_amdgcn_rcpf(__log2f((float)pos + 1.0f));
    }
    float dcg_p = (tid < 16) ? ws[b * 16 + tid] : 0.0f;
    fred[tid] = make_float2(idcg_p, dcg_p);
    __syncthreads();
    #pragma unroll
    for (int s = 128; s > 0; s >>= 1) {
        if (tid < (unsigned)s) {
            float2 a = fred[tid], c = fred[tid + s];
            fred[tid] = make_float2(a.x + c.x, a.y + c.y);
        }
        __syncthreads();
    }

    if (tid == 0) {
        float ndcg = fred[0].y / (fred[0].x + 1e-10f);
        atomicAdd(&ws[2048], ndcg);
        __threadfence();
        int old = atomicAdd((int*)ws + 2049, 1);
        if (old == B - 1) {
            float acc = atomicAdd(&ws[2048], 0.0f);  // coherent read of final sum
            out[0] = -acc * (1.0f / (float)B);
        }
    }
}

extern "C" void kernel_launch(void* const* d_in, const int* in_sizes, int n_in,
                              void* d_out, int out_size, void* d_ws, size_t ws_size,
                              hipStream_t stream) {
    const float* preds  = (const float*)d_in[0];
    const float* target = (const float*)d_in[1];
    float* out = (float*)d_out;
    float* ws  = (float*)d_ws;

    pair_kernel<<<B * 4, 256, 0, stream>>>(preds, target, ws);
    finish_kernel<<<B, 256, 0, stream>>>(target, ws, out);
}

// Round 4
// 95.673 us; speedup vs baseline: 2.3729x; 1.0124x over previous
//
#include <hip/hip_runtime.h>

#define B 128
#define L 1024

#if __has_builtin(__builtin_amdgcn_exp2f)
#define EXP2(x) __builtin_amdgcn_exp2f(x)
#else
#define EXP2(x) __expf((x) * 0.6931471805599453f)
#endif

// ws layout (floats):
//   [0..128)    dcg[b] accumulators
//   [128..256)  per-row completion counters (int)
//   [256]       ndcg accumulator
//   [257]       global completion counter (int)

__global__ __launch_bounds__(256) void init_ws(float* ws) {
    int t = threadIdx.x;
    ws[t] = 0.0f;
    if (t < 2) ws[256 + t] = 0.0f;
}

// Phi(diff/sqrt2) with y = diff/2 prescaled into LDS:
//   erfc(|y|) ~= exp(-(1.12838 y + 0.6446 y^2 + 0.0745 y^3)), |dPhi| <= ~2.5e-4
// Constants pre-multiplied by -log2(e) so v_exp_f32 computes exp2 directly.
// Per pair: sub, fma, fma, mul, exp2, subrev, bfi(copysign), add = 7 VALU + 1 trans.
#define K1 -1.6279072f
#define K2 -0.9299637f
#define K3 -0.1074808f

__device__ __forceinline__ float phi_term(float pi, float pj) {
    float d = pi - pj;                       // = y signed (inputs prescaled by 0.5)
    float a = __builtin_fabsf(d);            // folds to operand abs-modifiers
    float t = __builtin_fmaf(K3, a, K2);
    float u = __builtin_fmaf(t, a, K1);
    float e = EXP2(a * u);                   // ~= erfc(|y|), in (0,1]
    return __builtin_copysignf(1.0f - e, d); // = erf(y) = 2*Phi - 1
}

// grid = B*4 blocks, 256 threads. Block (b, iseg): i in [iseg*256, ...+256),
// full j range from LDS. Fused epilogue: per-row last block does IDCG + ndcg;
// last row overall writes the final scalar.
__global__ __launch_bounds__(256) void pair_fused_kernel(const float* __restrict__ preds,
                                                         const float* __restrict__ target,
                                                         float* __restrict__ ws,
                                                         float* __restrict__ out) {
    __shared__ float sp[L];
    __shared__ float wred[4];
    __shared__ int lastflag;
    __shared__ unsigned long long cred[256];
    __shared__ float fred[256];

    const int b    = blockIdx.x >> 2;
    const int iseg = blockIdx.x & 3;
    const int tid  = threadIdx.x;
    const float* prow = preds + b * L;
    const float* trow = target + b * L;

    // stage row prescaled by 0.5 (erf argument is diff/2)
    float4 v4 = reinterpret_cast<const float4*>(prow)[tid];
    v4.x *= 0.5f; v4.y *= 0.5f; v4.z *= 0.5f; v4.w *= 0.5f;
    reinterpret_cast<float4*>(sp)[tid] = v4;

    const int i = iseg * 256 + tid;
    const float tgt = trow[i];               // hoisted global load

    __syncthreads();

    const float pi = sp[i];

    float a0 = 0.f, a1 = 0.f, a2 = 0.f, a3 = 0.f,
          a4 = 0.f, a5 = 0.f, a6 = 0.f, a7 = 0.f;
    for (int j = 0; j < L; j += 8) {
        float4 va = *reinterpret_cast<const float4*>(&sp[j]);
        float4 vb = *reinterpret_cast<const float4*>(&sp[j + 4]);
        a0 += phi_term(pi, va.x);
        a1 += phi_term(pi, va.y);
        a2 += phi_term(pi, va.z);
        a3 += phi_term(pi, va.w);
        a4 += phi_term(pi, vb.x);
        a5 += phi_term(pi, vb.y);
        a6 += phi_term(pi, vb.z);
        a7 += phi_term(pi, vb.w);
    }
    float E = ((a0 + a1) + (a2 + a3)) + ((a4 + a5) + (a6 + a7));
    // sum_j Phi = L/2 + E/2 (diagonal contributes exactly 0.5);
    // expected_rank + 1 = 1 + (sum_j Phi - 0.5) + 1 = 513.5 + 0.5*E
    float er1 = 513.5f + 0.5f * E;

    float g = EXP2(tgt) - 1.0f;              // 2^t - 1, exact for integer grades
    float contrib = g * __builtin_amdgcn_rcpf(__log2f(er1));

    // wave reduce (64 lanes), then cross-wave via 4-slot LDS
    #pragma unroll
    for (int off = 32; off > 0; off >>= 1)
        contrib += __shfl_down(contrib, off);
    if ((tid & 63) == 0) wred[tid >> 6] = contrib;
    __syncthreads();

    if (tid == 0) {
        float blocksum = (wred[0] + wred[1]) + (wred[2] + wred[3]);
        atomicAdd(&ws[b], blocksum);
        __threadfence();
        int old = atomicAdd((int*)ws + 128 + b, 1);
        lastflag = (old == 3);
    }
    __syncthreads();

    if (!lastflag) return;

    // ---- per-row epilogue: counting-sort IDCG (grades are ints 0..4) ----
    unsigned long long cnt = 0ull;
    #pragma unroll
    for (int k = 0; k < 4; ++k) {
        float t = trow[tid + k * 256];
        cnt += ((unsigned long long)(t > 3.5f) << 48)
             + ((unsigned long long)(t > 2.5f) << 32)
             + ((unsigned long long)(t > 1.5f) << 16)
             + ((unsigned long long)(t > 0.5f));
    }
    cred[tid] = cnt;
    __syncthreads();
    #pragma unroll
    for (int s = 128; s > 0; s >>= 1) {
        if (tid < (unsigned)s) cred[tid] += cred[tid + s];
        __syncthreads();
    }
    unsigned long long tot = cred[0];
    const int n4 = (int)(tot >> 48) & 0xFFFF;
    const int n3 = (int)(tot >> 32) & 0xFFFF;
    const int n2 = (int)(tot >> 16) & 0xFFFF;
    const int n1 = (int)(tot)       & 0xFFFF;

    float idcg_p = 0.0f;
    #pragma unroll
    for (int k = 0; k < 4; ++k) {
        int pos = tid + 1 + k * 256;
        float gain = (pos <= n4) ? 15.0f : (pos <= n3) ? 7.0f :
                     (pos <= n2) ? 3.0f  : (pos <= n1) ? 1.0f : 0.0f;
        idcg_p += gain * __builtin_amdgcn_rcpf(__log2f((float)pos + 1.0f));
    }
    fred[tid] = idcg_p;
    __syncthreads();
    #pragma unroll
    for (int s = 128; s > 0; s >>= 1) {
        if (tid < (unsigned)s) fred[tid] += fred[tid + s];
        __syncthreads();
    }

    if (tid == 0) {
        __threadfence();                                  // acquire: order dcg reads after ctr
        float dcgv = atomicAdd(&ws[b], 0.0f);             // coherent read of completed dcg[b]
        float ndcg = dcgv / (fred[0] + 1e-10f);
        atomicAdd(&ws[256], ndcg);
        __threadfence();
        int old2 = atomicAdd((int*)ws + 257, 1);
        if (old2 == B - 1) {
            float acc = atomicAdd(&ws[256], 0.0f);        // coherent read of final sum
            out[0] = -acc * (1.0f / (float)B);
        }
    }
}

extern "C" void kernel_launch(void* const* d_in, const int* in_sizes, int n_in,
                              void* d_out, int out_size, void* d_ws, size_t ws_size,
                              hipStream_t stream) {
    const float* preds  = (const float*)d_in[0];
    const float* target = (const float*)d_in[1];
    float* out = (float*)d_out;
    float* ws  = (float*)d_ws;

    init_ws<<<1, 256, 0, stream>>>(ws);
    pair_fused_kernel<<<B * 4, 256, 0, stream>>>(preds, target, ws, out);
}